// Round 1
// baseline (972.434 us; speedup 1.0000x reference)
//
#include <hip/hip_runtime.h>

#define B_    2
#define S_    2048
#define H_    32
#define KVH_  8
#define D_    128
#define QB    64
#define KB    64
#define NREP  (H_ / KVH_)
#define SCALE 0.08838834764831845f  // 128^-0.5

// MFMA fragment types (gfx950, 16x16x32 bf16): 8 bf16 inputs (as short8), 4 f32 acc
typedef short  short8 __attribute__((ext_vector_type(8)));
typedef float  f32x4  __attribute__((ext_vector_type(4)));

// fp32 -> bf16 round-to-nearest-even (inputs are finite; no NaN handling needed)
__device__ inline unsigned short f2bf(float f) {
    unsigned int u = __float_as_uint(f);
    u += 0x7fffu + ((u >> 16) & 1u);
    return (unsigned short)(u >> 16);
}

// LDS layout (shorts):
//   Qsh: [QB][D+8]   stride 136  (reused as Psh [QB][KB+8] stride 72 after Q frags read)
//   Ksh: [KB][D+8]   stride 136  (row-major keys; +8 pad -> conflict-free b128 frag reads)
//   VT : [D][KB+8]   stride 72   (transposed V; b128 frag reads conflict-free)
#define QK_STRIDE (D_ + 8)
#define P_STRIDE  (KB + 8)
#define LDS_SHORTS (QB * QK_STRIDE + KB * QK_STRIDE + D_ * P_STRIDE)

__global__ __launch_bounds__(256, 3) void fa_kernel(
    const float* __restrict__ q, const float* __restrict__ k,
    const float* __restrict__ v, float* __restrict__ out) {

    __shared__ unsigned short sh[LDS_SHORTS];
    unsigned short* Qsh = sh;
    unsigned short* Ksh = sh + QB * QK_STRIDE;
    unsigned short* VT  = Ksh + KB * QK_STRIDE;
    unsigned short* Psh = sh;  // overlays Q buffer (Q frags live in regs by then)

    const int t    = threadIdx.x;
    const int wave = t >> 6;
    const int lane = t & 63;
    const int m16  = lane & 15;
    const int quad = lane >> 4;

    const int qt  = (S_ / QB - 1) - blockIdx.x;  // heavy tiles first
    const int bh  = blockIdx.y;
    const int b   = bh / H_;
    const int h   = bh % H_;
    const int kvh = h / NREP;
    const int qbase = qt * QB;

    // ---- stage Q tile (fp32 -> bf16), coalesced float4 reads ----
    {
        const float* qg = q + ((size_t)(b * S_ + qbase) * (H_ * D_)) + h * D_;
        #pragma unroll
        for (int it = 0; it < 8; ++it) {
            const int row = (t >> 5) + it * 8;
            const int c4  = (t & 31) * 4;
            const float4 val = *(const float4*)(qg + (size_t)row * (H_ * D_) + c4);
            ushort4 w;
            w.x = f2bf(val.x); w.y = f2bf(val.y); w.z = f2bf(val.z); w.w = f2bf(val.w);
            *(ushort4*)&Qsh[row * QK_STRIDE + c4] = w;
        }
    }
    __syncthreads();

    // ---- Q A-fragments into registers: A[m=lane&15][k=quad*8+j], 4 chunks of K=32 ----
    short8 qf[4];
    #pragma unroll
    for (int c = 0; c < 4; ++c)
        qf[c] = *(const short8*)&Qsh[(wave * 16 + m16) * QK_STRIDE + c * 32 + quad * 8];
    // NOTE: first k-tile's __syncthreads (below) orders all waves' qf reads before
    // any P write into this same buffer.

    f32x4 o[8];
    #pragma unroll
    for (int i = 0; i < 8; ++i) o[i] = (f32x4){0.f, 0.f, 0.f, 0.f};
    float m_i[4], l_i[4];
    #pragma unroll
    for (int r = 0; r < 4; ++r) { m_i[r] = -INFINITY; l_i[r] = 0.f; }

    const float* kg = k + (size_t)b * S_ * (KVH_ * D_) + kvh * D_;
    const float* vg = v + (size_t)b * S_ * (KVH_ * D_) + kvh * D_;

    for (int kt = 0; kt <= qt; ++kt) {
        const int kb = kt * KB;

        // ---- stage K tile row-major bf16 ----
        #pragma unroll
        for (int it = 0; it < 8; ++it) {
            const int row = (t >> 5) + it * 8;
            const int c4  = (t & 31) * 4;
            const float4 val = *(const float4*)(kg + (size_t)(kb + row) * (KVH_ * D_) + c4);
            ushort4 w;
            w.x = f2bf(val.x); w.y = f2bf(val.y); w.z = f2bf(val.z); w.w = f2bf(val.w);
            *(ushort4*)&Ksh[row * QK_STRIDE + c4] = w;
        }
        // ---- stage V transposed: VT[d][key] (coalesced global reads along d) ----
        {
            const int d    = t & 127;
            const int half = t >> 7;
            #pragma unroll
            for (int kk = 0; kk < 16; ++kk) {
                const int key0 = (kk + half * 16) * 2;
                const float v0 = vg[(size_t)(kb + key0)     * (KVH_ * D_) + d];
                const float v1 = vg[(size_t)(kb + key0 + 1) * (KVH_ * D_) + d];
                const unsigned int pack =
                    (unsigned int)f2bf(v0) | ((unsigned int)f2bf(v1) << 16);
                *(unsigned int*)&VT[d * P_STRIDE + key0] = pack;
            }
        }
        __syncthreads();

        // ---- S = Q K^T (C layout: row=quad*4+reg, col=m16) ----
        f32x4 sa[4];
        #pragma unroll
        for (int nt = 0; nt < 4; ++nt) sa[nt] = (f32x4){0.f, 0.f, 0.f, 0.f};
        #pragma unroll
        for (int c = 0; c < 4; ++c) {
            #pragma unroll
            for (int nt = 0; nt < 4; ++nt) {
                const short8 bfr = *(const short8*)
                    &Ksh[(nt * 16 + m16) * QK_STRIDE + c * 32 + quad * 8];
                sa[nt] = __builtin_amdgcn_mfma_f32_16x16x32_bf16(qf[c], bfr, sa[nt], 0, 0, 0);
            }
        }

        // ---- scale + causal mask ----
        const bool diag = (kt == qt);
        float p[4][4];
        #pragma unroll
        for (int nt = 0; nt < 4; ++nt) {
            #pragma unroll
            for (int r = 0; r < 4; ++r) {
                float sv = sa[nt][r] * SCALE;
                if (diag) {
                    const int rowg = qbase + wave * 16 + quad * 4 + r;
                    const int colg = kb + nt * 16 + m16;
                    if (colg > rowg) sv = -INFINITY;
                }
                p[nt][r] = sv;
            }
        }

        // ---- online softmax (row reductions across the 16 lanes of the quad) ----
        float alpha[4];
        #pragma unroll
        for (int r = 0; r < 4; ++r) {
            float mv = fmaxf(fmaxf(p[0][r], p[1][r]), fmaxf(p[2][r], p[3][r]));
            mv = fmaxf(mv, __shfl_xor(mv, 1));
            mv = fmaxf(mv, __shfl_xor(mv, 2));
            mv = fmaxf(mv, __shfl_xor(mv, 4));
            mv = fmaxf(mv, __shfl_xor(mv, 8));
            const float mnew = fmaxf(m_i[r], mv);
            alpha[r] = __expf(m_i[r] - mnew);   // m_i=-inf first tile -> alpha=0
            m_i[r] = mnew;
            float rs = 0.f;
            #pragma unroll
            for (int nt = 0; nt < 4; ++nt) {
                const float e = __expf(p[nt][r] - mnew);  // masked -inf -> 0
                p[nt][r] = e;
                rs += e;
            }
            rs += __shfl_xor(rs, 1);
            rs += __shfl_xor(rs, 2);
            rs += __shfl_xor(rs, 4);
            rs += __shfl_xor(rs, 8);
            l_i[r] = l_i[r] * alpha[r] + rs;
        }

        // ---- rescale O, write P (C layout -> LDS) ----
        #pragma unroll
        for (int dn = 0; dn < 8; ++dn)
            #pragma unroll
            for (int r = 0; r < 4; ++r)
                o[dn][r] *= alpha[r];

        #pragma unroll
        for (int nt = 0; nt < 4; ++nt)
            #pragma unroll
            for (int r = 0; r < 4; ++r)
                Psh[(wave * 16 + quad * 4 + r) * P_STRIDE + nt * 16 + m16] = f2bf(p[nt][r]);

        __syncthreads();  // order P write -> A-layout read (and keep staging disciplined)

        // ---- O += P V : A from Psh, B from VT ----
        #pragma unroll
        for (int c2 = 0; c2 < 2; ++c2) {
            const short8 pf = *(const short8*)
                &Psh[(wave * 16 + m16) * P_STRIDE + c2 * 32 + quad * 8];
            #pragma unroll
            for (int dn = 0; dn < 8; ++dn) {
                const short8 vf = *(const short8*)
                    &VT[(dn * 16 + m16) * P_STRIDE + c2 * 32 + quad * 8];
                o[dn] = __builtin_amdgcn_mfma_f32_16x16x32_bf16(pf, vf, o[dn], 0, 0, 0);
            }
        }
        __syncthreads();  // protect Ksh/VT/Psh before next tile's staging
    }

    // ---- epilogue: O /= l, store fp32 ----
    float inv[4];
    #pragma unroll
    for (int r = 0; r < 4; ++r) inv[r] = 1.f / l_i[r];
    float* og = out + ((size_t)(b * S_ + qbase) * (H_ * D_)) + h * D_;
    #pragma unroll
    for (int dn = 0; dn < 8; ++dn) {
        #pragma unroll
        for (int r = 0; r < 4; ++r) {
            const int row = wave * 16 + quad * 4 + r;
            og[(size_t)row * (H_ * D_) + dn * 16 + m16] = o[dn][r] * inv[r];
        }
    }
}

extern "C" void kernel_launch(void* const* d_in, const int* in_sizes, int n_in,
                              void* d_out, int out_size, void* d_ws, size_t ws_size,
                              hipStream_t stream) {
    const float* q = (const float*)d_in[0];
    const float* k = (const float*)d_in[1];
    const float* v = (const float*)d_in[2];
    float* out = (float*)d_out;
    dim3 grid(S_ / QB, B_ * H_);
    fa_kernel<<<grid, dim3(256), 0, stream>>>(q, k, v, out);
}